// Round 1
// baseline (9.441 us; speedup 1.0000x reference)
//
#include <hip/hip_runtime.h>
#include <hip/hip_bf16.h>

// out[b, j] = tokens[b, idx[b, j], j]
// tokens: [B, S, E] fp32,  idx: [B, E] int32,  out: [B, E] fp32
// B=64, S=512, E=1024  (but read sizes from in_sizes to stay generic)

__global__ void embrace_gather_kernel(const float* __restrict__ tokens,
                                      const int* __restrict__ idx,
                                      float* __restrict__ out,
                                      int S, int E, int total /* = B*E */) {
    int i = blockIdx.x * blockDim.x + threadIdx.x;
    if (i >= total) return;
    int b = i / E;
    int j = i - b * E;
    int s = idx[i];                       // coalesced: idx is [B,E] row-major
    out[i] = tokens[(size_t)b * S * E + (size_t)s * E + j];  // gather
}

extern "C" void kernel_launch(void* const* d_in, const int* in_sizes, int n_in,
                              void* d_out, int out_size, void* d_ws, size_t ws_size,
                              hipStream_t stream) {
    const float* tokens = (const float*)d_in[0];   // [B, S, E]
    const int*   idx    = (const int*)d_in[1];     // [B, E]
    float*       out    = (float*)d_out;           // [B, E]

    const int total = out_size;            // B*E = 65536
    const int BE    = in_sizes[1];         // B*E
    const int E     = 1024;
    const int B     = BE / E;
    const int S     = in_sizes[0] / (B * E);   // 512

    const int block = 256;
    const int grid  = (total + block - 1) / block;
    embrace_gather_kernel<<<grid, block, 0, stream>>>(tokens, idx, out, S, E, total);
}